// Round 2
// baseline (208.872 us; speedup 1.0000x reference)
//
#include <hip/hip_runtime.h>

// DR splitting solver. BATCH=4096, N=96 (64 x + 32 s), M=48 (16 eq + 32 ineq).
// JF and Hessian are batch-independent => prox_g1 is an affine map y = P x + Bmat p.
//   S=(I+Q)^{-1}; T=S Jx^T; K2=Jx T+diag(0,I32); R2=K2^{-1}[T^T|E];
//   P=diag(S,I)-[T;E^T]R2; Bmat=[-P[:,:64] | R2^T]   (uses I-P*Md = Md^{-1}J^T K2^{-1} J)
// Iterate 10x: y=Px+c; x += clamp(2y-x,l,u)-y; out=y[:64].
//
// prep is 1 block: ALL loops rolled (round-1 lesson: fully-unrolled solves made
// ~100KB straight-line code -> cold I-fetch dominated, 157us). Inverses computed
// as S = Xt Xt^T with Xt = (L^{-1})^T from a rolled forward solve (lane-private
// rows, no cross-lane sync), then parallel tiled matmuls on 256 threads.

__device__ __forceinline__ float dot4f(float4 a, float4 b) {
  return a.x*b.x + a.y*b.y + a.z*b.z + a.w*b.w;
}
__device__ __forceinline__ void ld4(const float* p, float* d) {
  float4 v = *(const float4*)p;
  d[0] = v.x; d[1] = v.y; d[2] = v.z; d[3] = v.w;
}

// ---------------------------------------------------------------- kernel A
__global__ __launch_bounds__(256) void prep_kernel(
    const float* __restrict__ Qg, const float* __restrict__ Ag,
    const float* __restrict__ Gg,
    float* __restrict__ Pg, float* __restrict__ Bg, float* __restrict__ R2g)
{
  // LDS budget (floats): bufA 4352 + bufB 4352 + sS 4352 + sT 3072 + sDi 64
  //                    = 16192 floats = 64768 B  (<= 64KB static cap)
  __shared__ float bufA[64*68];   // L (64x68) -> later K2 chol (48x52) -> Ki (48x52)
  __shared__ float bufB[64*68];   // Xt (64x68) -> later Yt (48x52)
  __shared__ float sS[64*68];     // S, live to the end
  __shared__ float sT[64*48];     // T, live to the end
  __shared__ float sDi[64];       // 1/diag of current chol factor

#define L_(i,j)  bufA[(i)*68+(j)]
#define XT_(c,i) bufB[(c)*68+(i)]
#define SS_(i,j) sS[(i)*68+(j)]
#define TT_(i,j) sT[(i)*48+(j)]
#define KK_(i,j) bufA[(i)*52+(j)]
#define YT_(c,i) bufB[(c)*52+(i)]
#define KI_(i,j) bufA[(i)*52+(j)]   // overlays KK (K dead once Yt is solved)

  const int tid = threadIdx.x;

  // ---- phase 1: M1 = Q + I
  for (int t = tid; t < 64*64; t += 256) {
    int i = t >> 6, j = t & 63;
    L_(i,j) = Qg[t] + (i == j ? 1.0f : 0.0f);
  }
  __syncthreads();

  // ---- phase 2: chol64 in place (wave 0, rolled)
  if (tid < 64) {
    #pragma unroll 1
    for (int j = 0; j < 64; ++j) {
      float tmp = 0.0f;
      if (tid >= j) {
        tmp = L_(tid,j);
        int j4 = j & ~3;
        #pragma unroll 1
        for (int k = 0; k < j4; k += 4)
          tmp -= dot4f(*(const float4*)&L_(tid,k), *(const float4*)&L_(j,k));
        for (int k = j4; k < j; ++k) tmp -= L_(tid,k) * L_(j,k);
      }
      float d = sqrtf(__shfl(tmp, j, 64));
      if (tid >= j) L_(tid,j) = (tid == j) ? d : tmp / d;
      __builtin_amdgcn_wave_barrier();
    }
    sDi[tid] = 1.0f / L_(tid,tid);
  }
  __syncthreads();

  // ---- phase 3: Xt = (L^{-1})^T via forward solve; lane c owns row c (private)
  // Xt[c][i] = X[i][c]; zeros appear naturally for i<c (acc sums zero terms).
  if (tid < 64) {
    const int c = tid;
    #pragma unroll 1
    for (int i = 0; i < 64; ++i) {
      float acc = (i == c) ? 1.0f : 0.0f;
      int i4 = i & ~3;
      #pragma unroll 1
      for (int j = 0; j < i4; j += 4)
        acc -= dot4f(*(const float4*)&L_(i,j), *(const float4*)&XT_(c,j));
      for (int j = i4; j < i; ++j) acc -= L_(i,j) * XT_(c,j);
      XT_(c,i) = acc * sDi[i];
    }
  }
  __syncthreads();

  // ---- phase 4: S = Xt Xt^T (256 threads, 4x4 tiles); Xt[r][k]=0 for k<r
  {
    int i0 = (tid >> 4) * 4, j0 = (tid & 15) * 4;
    float acc[4][4] = {};
    int k0 = (i0 > j0) ? i0 : j0;   // already a multiple of 4
    #pragma unroll 1
    for (int k = k0; k < 64; k += 4) {
      float a[4][4], b[4][4];
      ld4(&XT_(i0+0,k), a[0]); ld4(&XT_(i0+1,k), a[1]);
      ld4(&XT_(i0+2,k), a[2]); ld4(&XT_(i0+3,k), a[3]);
      ld4(&XT_(j0+0,k), b[0]); ld4(&XT_(j0+1,k), b[1]);
      ld4(&XT_(j0+2,k), b[2]); ld4(&XT_(j0+3,k), b[3]);
      #pragma unroll
      for (int r = 0; r < 4; ++r)
        #pragma unroll
        for (int q = 0; q < 4; ++q)
          #pragma unroll
          for (int s = 0; s < 4; ++s)
            acc[r][q] += a[r][s] * b[q][s];
    }
    #pragma unroll
    for (int r = 0; r < 4; ++r)
      #pragma unroll
      for (int q = 0; q < 4; ++q)
        SS_(i0+r, j0+q) = acc[r][q];
  }
  __syncthreads();

  // ---- phase 5: T = S Jx^T  (T[i][j] = sum_k S[i][k]*Jx[j][k])
  for (int t = tid; t < 64*48; t += 256) {
    int i = t / 48, j = t - i*48;
    const float* jx = (j < 16) ? (Ag + (j << 6)) : (Gg + ((j - 16) << 6));
    float acc = 0.0f;
    #pragma unroll 1
    for (int k = 0; k < 64; k += 4)
      acc += dot4f(*(const float4*)&SS_(i,k), *(const float4*)(jx + k));
    TT_(i,j) = acc;
  }
  __syncthreads();

  // ---- phase 6: K2 = Jx T + diag(0,I32)  (192 threads, 3x4 tiles)
  if (tid < 192) {
    int ag = tid / 12, bg = tid - ag*12;
    int a0 = ag*3, b0 = bg*4;
    float acc[3][4] = {};
    const float* ja[3];
    #pragma unroll
    for (int r = 0; r < 3; ++r) {
      int a = a0 + r;
      ja[r] = (a < 16) ? (Ag + (a << 6)) : (Gg + ((a - 16) << 6));
    }
    #pragma unroll 1
    for (int k = 0; k < 64; ++k) {
      float4 tb = *(const float4*)&TT_(k,b0);
      #pragma unroll
      for (int r = 0; r < 3; ++r) {
        float jv = ja[r][k];
        acc[r][0] += jv*tb.x; acc[r][1] += jv*tb.y;
        acc[r][2] += jv*tb.z; acc[r][3] += jv*tb.w;
      }
    }
    #pragma unroll
    for (int r = 0; r < 3; ++r)
      #pragma unroll
      for (int q = 0; q < 4; ++q) {
        int a = a0 + r, b = b0 + q;
        KK_(a,b) = acc[r][q] + ((a == b && a >= 16) ? 1.0f : 0.0f);
      }
  }
  __syncthreads();

  // ---- phase 7: chol48 in place (wave 0, rolled)
  if (tid < 48) {
    #pragma unroll 1
    for (int j = 0; j < 48; ++j) {
      float tmp = 0.0f;
      if (tid >= j) {
        tmp = KK_(tid,j);
        int j4 = j & ~3;
        #pragma unroll 1
        for (int k = 0; k < j4; k += 4)
          tmp -= dot4f(*(const float4*)&KK_(tid,k), *(const float4*)&KK_(j,k));
        for (int k = j4; k < j; ++k) tmp -= KK_(tid,k) * KK_(j,k);
      }
      float d = sqrtf(__shfl(tmp, j, 64));
      if (tid >= j) KK_(tid,j) = (tid == j) ? d : tmp / d;
      __builtin_amdgcn_wave_barrier();
    }
    sDi[tid] = 1.0f / KK_(tid,tid);
  }
  __syncthreads();

  // ---- phase 8: Yt = (Kc^{-1})^T via forward solve (lanes 0..47)
  if (tid < 48) {
    const int c = tid;
    #pragma unroll 1
    for (int i = 0; i < 48; ++i) {
      float acc = (i == c) ? 1.0f : 0.0f;
      int i4 = i & ~3;
      #pragma unroll 1
      for (int j = 0; j < i4; j += 4)
        acc -= dot4f(*(const float4*)&KK_(i,j), *(const float4*)&YT_(c,j));
      for (int j = i4; j < i; ++j) acc -= KK_(i,j) * YT_(c,j);
      YT_(c,i) = acc * sDi[i];
    }
  }
  __syncthreads();

  // ---- phase 9: Ki = Yt Yt^T (256 threads, 3x3 tiles over 48x48)
  {
    int i0 = (tid >> 4) * 3, j0 = (tid & 15) * 3;
    float acc[3][3] = {};
    int kst = ((i0 > j0) ? i0 : j0) & ~3;
    #pragma unroll 1
    for (int k = kst; k < 48; k += 4) {
      float a[3][4], b[3][4];
      ld4(&YT_(i0+0,k), a[0]); ld4(&YT_(i0+1,k), a[1]); ld4(&YT_(i0+2,k), a[2]);
      ld4(&YT_(j0+0,k), b[0]); ld4(&YT_(j0+1,k), b[1]); ld4(&YT_(j0+2,k), b[2]);
      #pragma unroll
      for (int r = 0; r < 3; ++r)
        #pragma unroll
        for (int q = 0; q < 3; ++q)
          #pragma unroll
          for (int s = 0; s < 4; ++s)
            acc[r][q] += a[r][s] * b[q][s];
    }
    __syncthreads();   // all reads of Yt/KK done before KI overlays bufA
    #pragma unroll
    for (int r = 0; r < 3; ++r)
      #pragma unroll
      for (int q = 0; q < 3; ++q)
        KI_(i0+r, j0+q) = acc[r][q];
  }
  __syncthreads();

  // ---- phase 10: R2 cols<64: R2[k][c] = sum_m Ki[k][m]*T[c][m]  (3k x 4c)
  {
    int kg = tid >> 4, cg = tid & 15;
    int k0 = kg*3, c0 = cg*4;
    float acc[3][4] = {};
    #pragma unroll 1
    for (int m = 0; m < 48; m += 4) {
      float kv[3][4], tv[4][4];
      ld4(&KI_(k0+0,m), kv[0]); ld4(&KI_(k0+1,m), kv[1]); ld4(&KI_(k0+2,m), kv[2]);
      ld4(&TT_(c0+0,m), tv[0]); ld4(&TT_(c0+1,m), tv[1]);
      ld4(&TT_(c0+2,m), tv[2]); ld4(&TT_(c0+3,m), tv[3]);
      #pragma unroll
      for (int r = 0; r < 3; ++r)
        #pragma unroll
        for (int q = 0; q < 4; ++q)
          #pragma unroll
          for (int s = 0; s < 4; ++s)
            acc[r][q] += kv[r][s] * tv[q][s];
    }
    #pragma unroll
    for (int r = 0; r < 3; ++r)
      #pragma unroll
      for (int q = 0; q < 4; ++q) {
        int k = k0 + r, c = c0 + q;
        float v = acc[r][q];
        R2g[k*96 + c] = v;
        Bg[c*112 + 64 + k] = v;       // Bmat[:,64:] = R2^T
      }
  }
  // R2 cols>=64 (selection from Ki)
  for (int t = tid; t < 48*32; t += 256) {
    int k = t >> 5, j = t & 31;
    float v = KI_(k, 16 + j);
    R2g[k*96 + 64 + j] = v;
    Bg[(64 + j)*112 + 64 + k] = v;
  }
  __syncthreads();

  // ---- phase 11: P heavy rows (i<64): P = S_diag - T*R2  (16 ig x 24 jc tasks)
  #pragma unroll 1
  for (int task = tid; task < 384; task += 256) {
    int ig = task / 24, jc = task - ig*24;
    int i0 = ig*4, j0 = jc*4;
    float acc[4][4];
    #pragma unroll
    for (int r = 0; r < 4; ++r)
      #pragma unroll
      for (int q = 0; q < 4; ++q)
        acc[r][q] = (j0 < 64) ? SS_(i0+r, j0+q) : 0.0f;
    #pragma unroll 1
    for (int m = 0; m < 48; m += 4) {
      float tv[4][4], rv[4][4];
      ld4(&TT_(i0+0,m), tv[0]); ld4(&TT_(i0+1,m), tv[1]);
      ld4(&TT_(i0+2,m), tv[2]); ld4(&TT_(i0+3,m), tv[3]);
      ld4(&R2g[(m+0)*96 + j0], rv[0]);
      ld4(&R2g[(m+1)*96 + j0], rv[1]);
      ld4(&R2g[(m+2)*96 + j0], rv[2]);
      ld4(&R2g[(m+3)*96 + j0], rv[3]);
      #pragma unroll
      for (int r = 0; r < 4; ++r)
        #pragma unroll
        for (int q = 0; q < 4; ++q)
          #pragma unroll
          for (int s = 0; s < 4; ++s)
            acc[r][q] -= tv[r][s] * rv[s][q];
    }
    #pragma unroll
    for (int r = 0; r < 4; ++r)
      #pragma unroll
      for (int q = 0; q < 4; ++q) {
        int i = i0 + r, j = j0 + q;
        float v = acc[r][q];
        Pg[i*96 + j] = v;
        if (j0 < 64) Bg[i*112 + j] = -v;   // Bmat[:,:64] = -P[:,:64]
      }
  }
  // ---- phase 12: P rows >= 64: P[64+a][j] = (64+a==j) - R2[16+a][j]
  for (int t = tid; t < 32*96; t += 256) {
    int a = t / 96, j = t - a*96;
    float v = ((64 + a) == j ? 1.0f : 0.0f) - R2g[(16 + a)*96 + j];
    Pg[(64 + a)*96 + j] = v;
    if (j < 64) Bg[(64 + a)*112 + j] = -v;
  }
#undef L_
#undef XT_
#undef SS_
#undef TT_
#undef KK_
#undef YT_
#undef KI_
}

// ---------------------------------------------------------------- kernel B
#define EB 16   // elements per block

__global__ __launch_bounds__(256) void iter_kernel(
    const float* __restrict__ xg, const float* __restrict__ pg,
    const float* __restrict__ Pg, const float* __restrict__ Bg,
    float* __restrict__ outg)
{
  __shared__ float sP[96][100];
  __shared__ float sX[EB][100];
  __shared__ float sC[EB][96];
  __shared__ float sPar[EB][112];

  const int tid = threadIdx.x;
  const int gbase = blockIdx.x * EB;

  // stage P, x, parms
  const float4* P4 = (const float4*)Pg;
  for (int t = tid; t < 96*24; t += 256) {
    int r = t / 24, kc = t - r*24;
    *(float4*)&sP[r][kc*4] = P4[t];
  }
  const float4* X4 = (const float4*)xg;
  for (int t = tid; t < EB*24; t += 256) {
    int e = t / 24, kc = t - e*24;
    *(float4*)&sX[e][kc*4] = X4[(gbase + e)*24 + kc];
  }
  const float4* Par4 = (const float4*)pg;
  for (int t = tid; t < EB*28; t += 256) {
    int e = t / 28, jc = t - e*28;
    *(float4*)&sPar[e][jc*4] = Par4[(gbase + e)*28 + jc];
  }
  __syncthreads();

  const int tr = tid & 31, te = tid >> 5;
  const int r0 = tr*3, e0 = te*2;

  // c = Bmat @ parms  (each thread: 3 rows x 2 elems)
  {
    const float4* B4 = (const float4*)Bg;
    #pragma unroll
    for (int rr = 0; rr < 3; ++rr) {
      int r = r0 + rr;
      float a0 = 0.0f, a1 = 0.0f;
      for (int jc = 0; jc < 28; ++jc) {
        float4 bm = B4[r*28 + jc];
        float4 p0 = *(const float4*)&sPar[e0][jc*4];
        float4 p1 = *(const float4*)&sPar[e0+1][jc*4];
        a0 += dot4f(bm, p0);
        a1 += dot4f(bm, p1);
      }
      sC[e0][r] = a0;
      sC[e0+1][r] = a1;
    }
  }
  __syncthreads();

  // 10 DR iterations
  for (int it = 0; it < 10; ++it) {
    float acc[3][2];
    #pragma unroll
    for (int rr = 0; rr < 3; ++rr) {
      acc[rr][0] = sC[e0][r0+rr];
      acc[rr][1] = sC[e0+1][r0+rr];
    }
    #pragma unroll
    for (int kc = 0; kc < 24; ++kc) {
      float pv[3][4], xv[2][4];
      ld4(&sP[r0+0][kc*4], pv[0]);
      ld4(&sP[r0+1][kc*4], pv[1]);
      ld4(&sP[r0+2][kc*4], pv[2]);
      ld4(&sX[e0+0][kc*4], xv[0]);
      ld4(&sX[e0+1][kc*4], xv[1]);
      #pragma unroll
      for (int rr = 0; rr < 3; ++rr)
        #pragma unroll
        for (int ee = 0; ee < 2; ++ee)
          #pragma unroll
          for (int s = 0; s < 4; ++s)
            acc[rr][ee] += pv[rr][s] * xv[ee][s];
    }

    if (it < 9) {
      __syncthreads();   // all dot reads of sX done
      #pragma unroll
      for (int rr = 0; rr < 3; ++rr) {
        int r = r0 + rr;
        float lo = (r < 64) ? -1000.0f : 0.0f;
        #pragma unroll
        for (int ee = 0; ee < 2; ++ee) {
          int e = e0 + ee;
          float y  = acc[rr][ee];
          float xo = sX[e][r];
          float v  = 2.0f*y - xo;
          float zc = fminf(fmaxf(v, lo), 1000.0f);
          sX[e][r] = xo + zc - y;
        }
      }
      __syncthreads();   // updates visible for next iteration
    } else {
      #pragma unroll
      for (int rr = 0; rr < 3; ++rr) {
        int r = r0 + rr;
        if (r < 64) {
          outg[(gbase + e0    )*64 + r] = acc[rr][0];
          outg[(gbase + e0 + 1)*64 + r] = acc[rr][1];
        }
      }
    }
  }
}

// ---------------------------------------------------------------- launch
extern "C" void kernel_launch(void* const* d_in, const int* in_sizes, int n_in,
                              void* d_out, int out_size, void* d_ws, size_t ws_size,
                              hipStream_t stream) {
  const float* x     = (const float*)d_in[0];   // (4096, 96)
  const float* parms = (const float*)d_in[1];   // (4096, 112)
  const float* Qg    = (const float*)d_in[2];   // (64, 64)
  const float* Ag    = (const float*)d_in[3];   // (16, 64)
  const float* Gg    = (const float*)d_in[4];   // (32, 64)
  float* out = (float*)d_out;                   // (4096, 64)

  float* ws  = (float*)d_ws;
  float* Pg  = ws;               // 96*96  = 9216
  float* Bg  = ws + 9216;        // 96*112 = 10752
  float* R2g = ws + 9216 + 10752;// 48*96  = 4608

  prep_kernel<<<1, 256, 0, stream>>>(Qg, Ag, Gg, Pg, Bg, R2g);
  iter_kernel<<<4096 / EB, 256, 0, stream>>>(x, parms, Pg, Bg, out);
}

// Round 3
// 135.428 us; speedup vs baseline: 1.5423x; 1.5423x over previous
//
#include <hip/hip_runtime.h>

// DR splitting solver. BATCH=4096, N=96 (64 x + 32 s), M=48 (16 eq + 32 ineq).
// JF and Hessian are batch-independent => prox_g1 is an affine map y = P x + Bmat p.
//   S=(I+Q)^{-1}; T=S Jx^T; K2=Jx T+diag(0,I32); R2=K2^{-1}[T^T|E];
//   P=diag(S,I)-[T;E^T]R2; Bmat=[-P[:,:64] | R2^T]
// Iterate 10x: y=Px+c; x += clamp(2y-x,l,u)-y; out=y[:64].
//
// Round-2 lesson: chol+triangular solves are LATENCY-serial (~1600 dependent
// LDS roundtrips, 1 wave) -> 174us. Replaced with in-place Gauss-Jordan:
// each pivot updates all elements in parallel (256 thr), 2 barriers/pivot,
// 112 pivots total. No pivoting needed: M1 >= I, K2 SPD.
// Round-3 iter fix: rotation-swizzled P layout ((kc+r)%24, row stride 24 quads)
// kills the 4-way quad-bank conflict on the dominant ds_read_b128 stream.

__device__ __forceinline__ float dot4f(float4 a, float4 b) {
  return a.x*b.x + a.y*b.y + a.z*b.z + a.w*b.w;
}
__device__ __forceinline__ void ld4(const float* p, float* d) {
  float4 v = *(const float4*)p;
  d[0] = v.x; d[1] = v.y; d[2] = v.z; d[3] = v.w;
}

// ---------------------------------------------------------------- kernel A
__global__ __launch_bounds__(256) void prep_kernel(
    const float* __restrict__ Qg, const float* __restrict__ Ag,
    const float* __restrict__ Gg,
    float* __restrict__ Pg, float* __restrict__ Bg)
{
  // LDS: sM 17408 + sT 12288 + sK 9984 + sR2 18432 + sCol/sRow 528 = 58640 B
  __shared__ float sM[64*68];    // M1 = I+Q  --GJ-->  S      (stride 68)
  __shared__ float sT[64*48];    // T = S Jx^T                (stride 48)
  __shared__ float sK[48*52];    // K2        --GJ-->  Ki     (stride 52)
  __shared__ float sR2[48*96];   // R2                        (stride 96)
  __shared__ float sCol[64];
  __shared__ float sRow[68];

#define SM_(i,j) sM[(i)*68+(j)]
#define TT_(i,j) sT[(i)*48+(j)]
#define SK_(i,j) sK[(i)*52+(j)]

  const int tid = threadIdx.x;

  // ---- load M1 = Q + I
  for (int t = tid; t < 64*64; t += 256) {
    int i = t >> 6, j = t & 63;
    SM_(i,j) = Qg[t] + (i == j ? 1.0f : 0.0f);
  }
  __syncthreads();

  // ---- GJ64: sM <- sM^{-1}. 4x4 tile per thread.
  {
    const int ig = tid >> 4, jg = tid & 15;     // rows 4ig.., cols 4jg..
    #pragma unroll 1
    for (int j = 0; j < 64; ++j) {
      float pi = 1.0f / SM_(j,j);               // broadcast read
      if (tid < 64) {
        sCol[tid] = (tid == j) ? 0.0f : SM_(tid,j);
      } else if (tid < 128) {
        int k = tid - 64;
        sRow[k] = (k == j) ? pi : SM_(j,k) * pi;
      }
      __syncthreads();
      float r4[4], c4[4];
      ld4(&sRow[4*jg], r4);
      ld4(&sCol[4*ig], c4);
      #pragma unroll
      for (int rr = 0; rr < 4; ++rr) {
        int i = 4*ig + rr;
        float a[4];
        ld4(&SM_(i, 4*jg), a);
        #pragma unroll
        for (int q = 0; q < 4; ++q) {
          int k = 4*jg + q;
          float v = a[q] - c4[rr] * r4[q];
          if (k == j) v = -c4[rr] * pi;
          if (i == j) v = r4[q];
          a[q] = v;
        }
        *(float4*)&SM_(i, 4*jg) = make_float4(a[0], a[1], a[2], a[3]);
      }
      __syncthreads();
    }
  }

  // ---- T = S Jx^T : T[i][j] = sum_k S[i][k]*Jx[j][k]
  for (int t = tid; t < 64*48; t += 256) {
    int i = t / 48, j = t - i*48;
    const float* jx = (j < 16) ? (Ag + (j << 6)) : (Gg + ((j - 16) << 6));
    float acc = 0.0f;
    #pragma unroll 1
    for (int k = 0; k < 64; k += 4)
      acc += dot4f(*(const float4*)&SM_(i,k), *(const float4*)(jx + k));
    TT_(i,j) = acc;
  }
  __syncthreads();

  // ---- K2 = Jx T + diag(0,I32)  (192 threads, 3x4 tiles)
  if (tid < 192) {
    int ag = tid / 12, bg = tid - ag*12;
    int a0 = ag*3, b0 = bg*4;
    float acc[3][4] = {};
    const float* ja[3];
    #pragma unroll
    for (int r = 0; r < 3; ++r) {
      int a = a0 + r;
      ja[r] = (a < 16) ? (Ag + (a << 6)) : (Gg + ((a - 16) << 6));
    }
    #pragma unroll 1
    for (int k = 0; k < 64; ++k) {
      float4 tb = *(const float4*)&TT_(k,b0);
      #pragma unroll
      for (int r = 0; r < 3; ++r) {
        float jv = ja[r][k];
        acc[r][0] += jv*tb.x; acc[r][1] += jv*tb.y;
        acc[r][2] += jv*tb.z; acc[r][3] += jv*tb.w;
      }
    }
    #pragma unroll
    for (int r = 0; r < 3; ++r)
      #pragma unroll
      for (int q = 0; q < 4; ++q) {
        int a = a0 + r, b = b0 + q;
        SK_(a,b) = acc[r][q] + ((a == b && a >= 16) ? 1.0f : 0.0f);
      }
  }
  __syncthreads();

  // ---- GJ48: sK <- sK^{-1}. 192 threads, 3 rows x 4 cols per thread.
  {
    const int ig = tid / 12, jg = tid - (tid / 12) * 12;  // valid when tid<192
    #pragma unroll 1
    for (int j = 0; j < 48; ++j) {
      float pi = 1.0f / SK_(j,j);
      if (tid < 48) {
        sCol[tid] = (tid == j) ? 0.0f : SK_(tid,j);
      } else if (tid >= 64 && tid < 112) {
        int k = tid - 64;
        sRow[k] = (k == j) ? pi : SK_(j,k) * pi;
      }
      __syncthreads();
      if (tid < 192) {
        float r4[4], c3[3];
        ld4(&sRow[4*jg], r4);
        c3[0] = sCol[3*ig+0]; c3[1] = sCol[3*ig+1]; c3[2] = sCol[3*ig+2];
        #pragma unroll
        for (int rr = 0; rr < 3; ++rr) {
          int i = 3*ig + rr;
          float a[4];
          ld4(&SK_(i, 4*jg), a);
          #pragma unroll
          for (int q = 0; q < 4; ++q) {
            int k = 4*jg + q;
            float v = a[q] - c3[rr] * r4[q];
            if (k == j) v = -c3[rr] * pi;
            if (i == j) v = r4[q];
            a[q] = v;
          }
          *(float4*)&SK_(i, 4*jg) = make_float4(a[0], a[1], a[2], a[3]);
        }
      }
      __syncthreads();
    }
  }

  // ---- R2 cols<64: R2[k][c] = sum_m Ki[k][m]*T[c][m]  (3k x 4c tiles)
  {
    int kg = tid >> 4, cg = tid & 15;
    int k0 = kg*3, c0 = cg*4;
    float acc[3][4] = {};
    #pragma unroll 1
    for (int m = 0; m < 48; m += 4) {
      float kv[3][4], tv[4][4];
      ld4(&SK_(k0+0,m), kv[0]); ld4(&SK_(k0+1,m), kv[1]); ld4(&SK_(k0+2,m), kv[2]);
      ld4(&TT_(c0+0,m), tv[0]); ld4(&TT_(c0+1,m), tv[1]);
      ld4(&TT_(c0+2,m), tv[2]); ld4(&TT_(c0+3,m), tv[3]);
      #pragma unroll
      for (int r = 0; r < 3; ++r)
        #pragma unroll
        for (int q = 0; q < 4; ++q)
          #pragma unroll
          for (int s = 0; s < 4; ++s)
            acc[r][q] += kv[r][s] * tv[q][s];
    }
    #pragma unroll
    for (int r = 0; r < 3; ++r)
      #pragma unroll
      for (int q = 0; q < 4; ++q) {
        int k = k0 + r, c = c0 + q;
        float v = acc[r][q];
        sR2[k*96 + c] = v;
        Bg[c*112 + 64 + k] = v;       // Bmat[:,64:] = R2^T
      }
  }
  // R2 cols>=64 (selection from Ki)
  for (int t = tid; t < 48*32; t += 256) {
    int k = t >> 5, j = t & 31;
    float v = SK_(k, 16 + j);
    sR2[k*96 + 64 + j] = v;
    Bg[(64 + j)*112 + 64 + k] = v;
  }
  __syncthreads();

  // ---- P heavy rows (i<64): P = S_diag - T*R2  (16 ig x 24 jc tasks)
  #pragma unroll 1
  for (int task = tid; task < 384; task += 256) {
    int ig = task / 24, jc = task - ig*24;
    int i0 = ig*4, j0 = jc*4;
    float acc[4][4];
    #pragma unroll
    for (int r = 0; r < 4; ++r)
      #pragma unroll
      for (int q = 0; q < 4; ++q)
        acc[r][q] = (j0 < 64) ? SM_(i0+r, j0+q) : 0.0f;
    #pragma unroll 1
    for (int m = 0; m < 48; m += 4) {
      float tv[4][4], rv[4][4];
      ld4(&TT_(i0+0,m), tv[0]); ld4(&TT_(i0+1,m), tv[1]);
      ld4(&TT_(i0+2,m), tv[2]); ld4(&TT_(i0+3,m), tv[3]);
      ld4(&sR2[(m+0)*96 + j0], rv[0]);
      ld4(&sR2[(m+1)*96 + j0], rv[1]);
      ld4(&sR2[(m+2)*96 + j0], rv[2]);
      ld4(&sR2[(m+3)*96 + j0], rv[3]);
      #pragma unroll
      for (int r = 0; r < 4; ++r)
        #pragma unroll
        for (int q = 0; q < 4; ++q)
          #pragma unroll
          for (int s = 0; s < 4; ++s)
            acc[r][q] -= tv[r][s] * rv[s][q];
    }
    #pragma unroll
    for (int r = 0; r < 4; ++r)
      #pragma unroll
      for (int q = 0; q < 4; ++q) {
        int i = i0 + r, j = j0 + q;
        float v = acc[r][q];
        Pg[i*96 + j] = v;
        if (j0 < 64) Bg[i*112 + j] = -v;   // Bmat[:,:64] = -P[:,:64]
      }
  }
  // ---- P rows >= 64: P[64+a][j] = (64+a==j) - R2[16+a][j]
  for (int t = tid; t < 32*96; t += 256) {
    int a = t / 96, j = t - a*96;
    float v = ((64 + a) == j ? 1.0f : 0.0f) - sR2[(16 + a)*96 + j];
    Pg[(64 + a)*96 + j] = v;
    if (j < 64) Bg[(64 + a)*112 + j] = -v;
  }
#undef SM_
#undef TT_
#undef SK_
}

// ---------------------------------------------------------------- kernel B
#define EB 16   // elements per block

__global__ __launch_bounds__(256) void iter_kernel(
    const float* __restrict__ xg, const float* __restrict__ pg,
    const float* __restrict__ Pg, const float* __restrict__ Bg,
    float* __restrict__ outg)
{
  // P stored rotation-swizzled: chunk kc of row r lives at quad (kc+r)%24.
  // Row stride 24 quads (96 floats); quad-bank = (kc+r)%8; rows step by 3
  // per lane (3 coprime 8) -> conflict-free ds_read_b128.
  __shared__ float sPr[96*96];
  __shared__ float sX[EB][100];
  __shared__ float sC[EB][96];
  __shared__ float sPar[EB][112];

  const int tid = threadIdx.x;
  const int gbase = blockIdx.x * EB;

  // stage P (swizzled), x, parms
  const float4* P4 = (const float4*)Pg;
  for (int t = tid; t < 96*24; t += 256) {
    int r = t / 24, kc = t - r*24;
    int kr = kc + (r % 24); if (kr >= 24) kr -= 24;
    *(float4*)&sPr[r*96 + kr*4] = P4[t];
  }
  const float4* X4 = (const float4*)xg;
  for (int t = tid; t < EB*24; t += 256) {
    int e = t / 24, kc = t - e*24;
    *(float4*)&sX[e][kc*4] = X4[(gbase + e)*24 + kc];
  }
  const float4* Par4 = (const float4*)pg;
  for (int t = tid; t < EB*28; t += 256) {
    int e = t / 28, jc = t - e*28;
    *(float4*)&sPar[e][jc*4] = Par4[(gbase + e)*28 + jc];
  }
  __syncthreads();

  const int tr = tid & 31, te = tid >> 5;
  const int r0 = tr*3, e0 = te*2;
  const int rot0 = r0 % 24, rot1 = (r0+1) % 24, rot2 = (r0+2) % 24;

  // c = Bmat @ parms  (each thread: 3 rows x 2 elems)
  {
    const float4* B4 = (const float4*)Bg;
    #pragma unroll
    for (int rr = 0; rr < 3; ++rr) {
      int r = r0 + rr;
      float a0 = 0.0f, a1 = 0.0f;
      for (int jc = 0; jc < 28; ++jc) {
        float4 bm = B4[r*28 + jc];
        float4 p0 = *(const float4*)&sPar[e0][jc*4];
        float4 p1 = *(const float4*)&sPar[e0+1][jc*4];
        a0 += dot4f(bm, p0);
        a1 += dot4f(bm, p1);
      }
      sC[e0][r] = a0;
      sC[e0+1][r] = a1;
    }
  }
  __syncthreads();

  // 10 DR iterations
  for (int it = 0; it < 10; ++it) {
    float acc[3][2];
    #pragma unroll
    for (int rr = 0; rr < 3; ++rr) {
      acc[rr][0] = sC[e0][r0+rr];
      acc[rr][1] = sC[e0+1][r0+rr];
    }
    #pragma unroll
    for (int kc = 0; kc < 24; ++kc) {
      int q0 = kc + rot0; if (q0 >= 24) q0 -= 24;
      int q1 = kc + rot1; if (q1 >= 24) q1 -= 24;
      int q2 = kc + rot2; if (q2 >= 24) q2 -= 24;
      float pv[3][4], xv[2][4];
      ld4(&sPr[(r0+0)*96 + q0*4], pv[0]);
      ld4(&sPr[(r0+1)*96 + q1*4], pv[1]);
      ld4(&sPr[(r0+2)*96 + q2*4], pv[2]);
      ld4(&sX[e0+0][kc*4], xv[0]);
      ld4(&sX[e0+1][kc*4], xv[1]);
      #pragma unroll
      for (int rr = 0; rr < 3; ++rr)
        #pragma unroll
        for (int ee = 0; ee < 2; ++ee)
          #pragma unroll
          for (int s = 0; s < 4; ++s)
            acc[rr][ee] += pv[rr][s] * xv[ee][s];
    }

    if (it < 9) {
      __syncthreads();   // all dot reads of sX done
      #pragma unroll
      for (int rr = 0; rr < 3; ++rr) {
        int r = r0 + rr;
        float lo = (r < 64) ? -1000.0f : 0.0f;
        #pragma unroll
        for (int ee = 0; ee < 2; ++ee) {
          int e = e0 + ee;
          float y  = acc[rr][ee];
          float xo = sX[e][r];
          float v  = 2.0f*y - xo;
          float zc = fminf(fmaxf(v, lo), 1000.0f);
          sX[e][r] = xo + zc - y;
        }
      }
      __syncthreads();   // updates visible for next iteration
    } else {
      #pragma unroll
      for (int rr = 0; rr < 3; ++rr) {
        int r = r0 + rr;
        if (r < 64) {
          outg[(gbase + e0    )*64 + r] = acc[rr][0];
          outg[(gbase + e0 + 1)*64 + r] = acc[rr][1];
        }
      }
    }
  }
}

// ---------------------------------------------------------------- launch
extern "C" void kernel_launch(void* const* d_in, const int* in_sizes, int n_in,
                              void* d_out, int out_size, void* d_ws, size_t ws_size,
                              hipStream_t stream) {
  const float* x     = (const float*)d_in[0];   // (4096, 96)
  const float* parms = (const float*)d_in[1];   // (4096, 112)
  const float* Qg    = (const float*)d_in[2];   // (64, 64)
  const float* Ag    = (const float*)d_in[3];   // (16, 64)
  const float* Gg    = (const float*)d_in[4];   // (32, 64)
  float* out = (float*)d_out;                   // (4096, 64)

  float* ws  = (float*)d_ws;
  float* Pg  = ws;               // 96*96  = 9216
  float* Bg  = ws + 9216;        // 96*112 = 10752

  prep_kernel<<<1, 256, 0, stream>>>(Qg, Ag, Gg, Pg, Bg);
  iter_kernel<<<4096 / EB, 256, 0, stream>>>(x, parms, Pg, Bg, out);
}

// Round 4
// 95.843 us; speedup vs baseline: 2.1793x; 1.4130x over previous
//
#include <hip/hip_runtime.h>

// DR splitting solver. BATCH=4096, N=96 (64 x + 32 s), M=48 (16 eq + 32 ineq).
// JF and Hessian are batch-independent => prox_g1 is an affine map y = P x + Bmat p.
//   S=(I+Q)^{-1}; T=S Jx^T; K2=Jx T+diag(0,I32); R2=K2^{-1}[T^T|E];
//   P=diag(S,I)-[T;E^T]R2; Bmat=[-P[:,:64] | R2^T]
// Iterate 10x: y=Px+c; x += clamp(2y-x,l,u)-y; out=y[:64].
//
// Round-3 lesson: scalar GJ = 112 pivots x ~900cy serial latency chain = ~100us.
// Round-4: BLOCK Gauss-Jordan (4 pivots/step): 28 steps, per-step the 4x4 pivot
// block is inverted redundantly in every thread's registers (SPD => no pivoting),
// rank-4 update applied in parallel. Jx staged in LDS (stride 68, no bank alias).
// iter: c kept in registers (sC deleted); sX double-buffered -> 1 barrier/iter.

__device__ __forceinline__ float dot4f(float4 a, float4 b) {
  return a.x*b.x + a.y*b.y + a.z*b.z + a.w*b.w;
}
__device__ __forceinline__ void ld4(const float* p, float* d) {
  float4 v = *(const float4*)p;
  d[0] = v.x; d[1] = v.y; d[2] = v.z; d[3] = v.w;
}
__device__ __forceinline__ void st4(float* p, const float* s) {
  *(float4*)p = make_float4(s[0], s[1], s[2], s[3]);
}
// W = A*B (4x4)
__device__ __forceinline__ void mm4(float W[4][4], const float A[4][4], const float B[4][4]) {
  #pragma unroll
  for (int r = 0; r < 4; ++r)
    #pragma unroll
    for (int q = 0; q < 4; ++q) {
      float s = A[r][0]*B[0][q];
      #pragma unroll
      for (int k = 1; k < 4; ++k) s += A[r][k]*B[k][q];
      W[r][q] = s;
    }
}
// in-place 4x4 inverse by GJ, no pivoting (SPD principal blocks)
__device__ __forceinline__ void inv4(float D[4][4]) {
  #pragma unroll
  for (int p = 0; p < 4; ++p) {
    float pi = 1.0f / D[p][p];
    D[p][p] = pi;
    #pragma unroll
    for (int q = 0; q < 4; ++q) if (q != p) D[p][q] *= pi;
    #pragma unroll
    for (int i = 0; i < 4; ++i) if (i != p) {
      float f = D[i][p];
      #pragma unroll
      for (int q = 0; q < 4; ++q) if (q != p) D[i][q] -= f * D[p][q];
      D[i][p] = -f * pi;
    }
  }
}

// ---------------------------------------------------------------- kernel A
__global__ __launch_bounds__(256) void prep_kernel(
    const float* __restrict__ Qg, const float* __restrict__ Ag,
    const float* __restrict__ Gg,
    float* __restrict__ Pg, float* __restrict__ Bg)
{
  // LDS: sM 17408 + sT 12288 + sK 9984 + sR2 18432 = 58112 B
  __shared__ float sM[64*68];    // M1 = I+Q  --blockGJ-->  S   (stride 68)
  __shared__ float sT[64*48];    // T = S Jx^T                  (stride 48)
  __shared__ float sK[48*52];    // K2        --blockGJ-->  Ki  (stride 52)
  __shared__ float sR2[48*96];   // Jx staged (stride 68) -> later R2 (stride 96)

#define SM_(i,j) sM[(i)*68+(j)]
#define TT_(i,j) sT[(i)*48+(j)]
#define SK_(i,j) sK[(i)*52+(j)]
#define JX_(a,k) sR2[(a)*68+(k)]

  const int tid = threadIdx.x;

  // ---- stage Jx = [A;G] (48x64, stride 68) and M1 = Q + I (vectorized)
  {
    const float4* A4 = (const float4*)Ag;          // 256 quads
    const float4* G4 = (const float4*)Gg;          // 512 quads
    for (int t = tid; t < 256; t += 256) {
      int a = t >> 4, kc = t & 15;
      st4(&JX_(a, kc*4), (const float*)&A4[t]);
    }
    for (int t = tid; t < 512; t += 256) {
      int a = t >> 4, kc = t & 15;
      st4(&JX_(16 + a, kc*4), (const float*)&G4[t]);
    }
    const float4* Q4 = (const float4*)Qg;          // 1024 quads
    for (int t = tid; t < 1024; t += 256) {
      int i = t >> 4, kc = t & 15;
      st4(&SM_(i, kc*4), (const float*)&Q4[t]);
    }
  }
  __syncthreads();
  if (tid < 64) SM_(tid, tid) += 1.0f;
  __syncthreads();

  // ---- block-GJ 64: sM <- sM^{-1}.  16 steps, 4x4 tile per thread.
  {
    const int ig = tid >> 4, jg = tid & 15;
    #pragma unroll 1
    for (int b = 0; b < 16; ++b) {
      float D[4][4], C[4][4], R[4][4], T4[4][4];
      #pragma unroll
      for (int r = 0; r < 4; ++r) {
        ld4(&SM_(4*b + r, 4*b), D[r]);
        ld4(&SM_(4*ig + r, 4*b), C[r]);
        ld4(&SM_(4*b + r, 4*jg), R[r]);
        ld4(&SM_(4*ig + r, 4*jg), T4[r]);
      }
      inv4(D);
      float W[4][4];
      if (ig == b) {
        if (jg == b) {
          #pragma unroll
          for (int r = 0; r < 4; ++r)
            #pragma unroll
            for (int q = 0; q < 4; ++q) W[r][q] = D[r][q];
        } else {
          mm4(W, D, R);                       // Dinv * R
        }
      } else {
        float E[4][4];
        mm4(E, C, D);                         // C * Dinv
        if (jg == b) {
          #pragma unroll
          for (int r = 0; r < 4; ++r)
            #pragma unroll
            for (int q = 0; q < 4; ++q) W[r][q] = -E[r][q];
        } else {
          #pragma unroll
          for (int r = 0; r < 4; ++r)
            #pragma unroll
            for (int q = 0; q < 4; ++q) {
              float s = T4[r][q];
              #pragma unroll
              for (int k = 0; k < 4; ++k) s -= E[r][k] * R[k][q];
              W[r][q] = s;
            }
        }
      }
      __syncthreads();   // all reads done
      #pragma unroll
      for (int r = 0; r < 4; ++r) st4(&SM_(4*ig + r, 4*jg), W[r]);
      __syncthreads();   // writes visible
    }
  }

  // ---- T = S Jx^T : T[i][j] = sum_k S[i][k]*Jx[j][k]   (LDS only)
  #pragma unroll 1
  for (int t = tid; t < 64*48; t += 256) {
    int i = t / 48, j = t - i*48;
    float acc = 0.0f;
    #pragma unroll 1
    for (int k = 0; k < 64; k += 4)
      acc += dot4f(*(const float4*)&SM_(i,k), *(const float4*)&JX_(j,k));
    TT_(i,j) = acc;
  }
  __syncthreads();

  // ---- K2 = Jx T + diag(0,I32)  (192 threads, 3x4 tiles)
  if (tid < 192) {
    int ag = tid / 12, bg = tid - ag*12;
    int a0 = ag*3, b0 = bg*4;
    float acc[3][4] = {};
    #pragma unroll 1
    for (int k = 0; k < 64; ++k) {
      float4 tb = *(const float4*)&TT_(k,b0);
      #pragma unroll
      for (int r = 0; r < 3; ++r) {
        float jv = JX_(a0 + r, k);
        acc[r][0] += jv*tb.x; acc[r][1] += jv*tb.y;
        acc[r][2] += jv*tb.z; acc[r][3] += jv*tb.w;
      }
    }
    #pragma unroll
    for (int r = 0; r < 3; ++r)
      #pragma unroll
      for (int q = 0; q < 4; ++q) {
        int a = a0 + r, b = b0 + q;
        SK_(a,b) = acc[r][q] + ((a == b && a >= 16) ? 1.0f : 0.0f);
      }
  }
  __syncthreads();

  // ---- block-GJ 48: sK <- sK^{-1}.  12 steps, tiles on 144 threads.
  {
    const int act = (tid < 144);
    const int ig = tid / 12, jg = tid - (tid / 12) * 12;
    #pragma unroll 1
    for (int b = 0; b < 12; ++b) {
      float D[4][4], C[4][4], R[4][4], T4[4][4], W[4][4];
      if (act) {
        #pragma unroll
        for (int r = 0; r < 4; ++r) {
          ld4(&SK_(4*b + r, 4*b), D[r]);
          ld4(&SK_(4*ig + r, 4*b), C[r]);
          ld4(&SK_(4*b + r, 4*jg), R[r]);
          ld4(&SK_(4*ig + r, 4*jg), T4[r]);
        }
        inv4(D);
        if (ig == b) {
          if (jg == b) {
            #pragma unroll
            for (int r = 0; r < 4; ++r)
              #pragma unroll
              for (int q = 0; q < 4; ++q) W[r][q] = D[r][q];
          } else {
            mm4(W, D, R);
          }
        } else {
          float E[4][4];
          mm4(E, C, D);
          if (jg == b) {
            #pragma unroll
            for (int r = 0; r < 4; ++r)
              #pragma unroll
              for (int q = 0; q < 4; ++q) W[r][q] = -E[r][q];
          } else {
            #pragma unroll
            for (int r = 0; r < 4; ++r)
              #pragma unroll
              for (int q = 0; q < 4; ++q) {
                float s = T4[r][q];
                #pragma unroll
                for (int k = 0; k < 4; ++k) s -= E[r][k] * R[k][q];
                W[r][q] = s;
              }
          }
        }
      }
      __syncthreads();
      if (act) {
        #pragma unroll
        for (int r = 0; r < 4; ++r) st4(&SK_(4*ig + r, 4*jg), W[r]);
      }
      __syncthreads();
    }
  }
  // Jx (in sR2 region) is dead from here; sR2 becomes R2 (stride 96).

  // ---- R2 cols<64: R2[k][c] = sum_m Ki[k][m]*T[c][m]  (3k x 4c tiles)
  {
    int kg = tid >> 4, cg = tid & 15;
    int k0 = kg*3, c0 = cg*4;
    float acc[3][4] = {};
    #pragma unroll 1
    for (int m = 0; m < 48; m += 4) {
      float kv[3][4], tv[4][4];
      ld4(&SK_(k0+0,m), kv[0]); ld4(&SK_(k0+1,m), kv[1]); ld4(&SK_(k0+2,m), kv[2]);
      ld4(&TT_(c0+0,m), tv[0]); ld4(&TT_(c0+1,m), tv[1]);
      ld4(&TT_(c0+2,m), tv[2]); ld4(&TT_(c0+3,m), tv[3]);
      #pragma unroll
      for (int r = 0; r < 3; ++r)
        #pragma unroll
        for (int q = 0; q < 4; ++q)
          #pragma unroll
          for (int s = 0; s < 4; ++s)
            acc[r][q] += kv[r][s] * tv[q][s];
    }
    __syncthreads();   // Jx reads fully done before overlay writes
    #pragma unroll
    for (int r = 0; r < 3; ++r)
      #pragma unroll
      for (int q = 0; q < 4; ++q) {
        int k = k0 + r, c = c0 + q;
        float v = acc[r][q];
        sR2[k*96 + c] = v;
        Bg[c*112 + 64 + k] = v;       // Bmat[:,64:] = R2^T
      }
  }
  // R2 cols>=64 (selection from Ki)
  for (int t = tid; t < 48*32; t += 256) {
    int k = t >> 5, j = t & 31;
    float v = SK_(k, 16 + j);
    sR2[k*96 + 64 + j] = v;
    Bg[(64 + j)*112 + 64 + k] = v;
  }
  __syncthreads();

  // ---- P heavy rows (i<64): P = S_diag - T*R2  (16 ig x 24 jc tasks)
  #pragma unroll 1
  for (int task = tid; task < 384; task += 256) {
    int ig = task / 24, jc = task - ig*24;
    int i0 = ig*4, j0 = jc*4;
    float acc[4][4];
    #pragma unroll
    for (int r = 0; r < 4; ++r)
      #pragma unroll
      for (int q = 0; q < 4; ++q)
        acc[r][q] = (j0 < 64) ? SM_(i0+r, j0+q) : 0.0f;
    #pragma unroll 1
    for (int m = 0; m < 48; m += 4) {
      float tv[4][4], rv[4][4];
      ld4(&TT_(i0+0,m), tv[0]); ld4(&TT_(i0+1,m), tv[1]);
      ld4(&TT_(i0+2,m), tv[2]); ld4(&TT_(i0+3,m), tv[3]);
      ld4(&sR2[(m+0)*96 + j0], rv[0]);
      ld4(&sR2[(m+1)*96 + j0], rv[1]);
      ld4(&sR2[(m+2)*96 + j0], rv[2]);
      ld4(&sR2[(m+3)*96 + j0], rv[3]);
      #pragma unroll
      for (int r = 0; r < 4; ++r)
        #pragma unroll
        for (int q = 0; q < 4; ++q)
          #pragma unroll
          for (int s = 0; s < 4; ++s)
            acc[r][q] -= tv[r][s] * rv[s][q];
    }
    #pragma unroll
    for (int r = 0; r < 4; ++r)
      #pragma unroll
      for (int q = 0; q < 4; ++q) {
        int i = i0 + r, j = j0 + q;
        float v = acc[r][q];
        Pg[i*96 + j] = v;
        if (j0 < 64) Bg[i*112 + j] = -v;   // Bmat[:,:64] = -P[:,:64]
      }
  }
  // ---- P rows >= 64: P[64+a][j] = (64+a==j) - R2[16+a][j]
  for (int t = tid; t < 32*96; t += 256) {
    int a = t / 96, j = t - a*96;
    float v = ((64 + a) == j ? 1.0f : 0.0f) - sR2[(16 + a)*96 + j];
    Pg[(64 + a)*96 + j] = v;
    if (j < 64) Bg[(64 + a)*112 + j] = -v;
  }
#undef SM_
#undef TT_
#undef SK_
#undef JX_
}

// ---------------------------------------------------------------- kernel B
#define EB 16   // elements per block

__global__ __launch_bounds__(256) void iter_kernel(
    const float* __restrict__ xg, const float* __restrict__ pg,
    const float* __restrict__ Pg, const float* __restrict__ Bg,
    float* __restrict__ outg)
{
  // P rotation-swizzled: chunk kc of row r at quad (kc+r)%24, row stride 24
  // quads -> conflict-free ds_read_b128 (rows step by 3, coprime to 8).
  // sX double-buffered: dot reads cur, RMW writes nxt -> ONE barrier/iter.
  __shared__ float sPr[96*96];
  __shared__ float sXbuf[2][EB][100];
  __shared__ float sPar[EB][112];

  const int tid = threadIdx.x;
  const int gbase = blockIdx.x * EB;

  // stage P (swizzled), x, parms
  const float4* P4 = (const float4*)Pg;
  for (int t = tid; t < 96*24; t += 256) {
    int r = t / 24, kc = t - r*24;
    int kr = kc + (r % 24); if (kr >= 24) kr -= 24;
    *(float4*)&sPr[r*96 + kr*4] = P4[t];
  }
  const float4* X4 = (const float4*)xg;
  for (int t = tid; t < EB*24; t += 256) {
    int e = t / 24, kc = t - e*24;
    *(float4*)&sXbuf[0][e][kc*4] = X4[(gbase + e)*24 + kc];
  }
  const float4* Par4 = (const float4*)pg;
  for (int t = tid; t < EB*28; t += 256) {
    int e = t / 28, jc = t - e*28;
    *(float4*)&sPar[e][jc*4] = Par4[(gbase + e)*28 + jc];
  }
  __syncthreads();

  const int tr = tid & 31, te = tid >> 5;
  const int r0 = tr*3, e0 = te*2;
  const int rot0 = r0 % 24, rot1 = (r0+1) % 24, rot2 = (r0+2) % 24;

  // c = Bmat @ parms, kept in registers (this thread consumes exactly these)
  float cc[3][2];
  {
    const float4* B4 = (const float4*)Bg;
    #pragma unroll
    for (int rr = 0; rr < 3; ++rr) {
      int r = r0 + rr;
      float a0 = 0.0f, a1 = 0.0f;
      #pragma unroll 1
      for (int jc = 0; jc < 28; ++jc) {
        float4 bm = B4[r*28 + jc];
        a0 += dot4f(bm, *(const float4*)&sPar[e0][jc*4]);
        a1 += dot4f(bm, *(const float4*)&sPar[e0+1][jc*4]);
      }
      cc[rr][0] = a0; cc[rr][1] = a1;
    }
  }

  float* cur = &sXbuf[0][0][0];
  float* nxt = &sXbuf[1][0][0];

  // 10 DR iterations, one barrier each
  for (int it = 0; it < 10; ++it) {
    float acc[3][2];
    #pragma unroll
    for (int rr = 0; rr < 3; ++rr) {
      acc[rr][0] = cc[rr][0];
      acc[rr][1] = cc[rr][1];
    }
    #pragma unroll
    for (int kc = 0; kc < 24; ++kc) {
      int q0 = kc + rot0; if (q0 >= 24) q0 -= 24;
      int q1 = kc + rot1; if (q1 >= 24) q1 -= 24;
      int q2 = kc + rot2; if (q2 >= 24) q2 -= 24;
      float pv[3][4], xv[2][4];
      ld4(&sPr[(r0+0)*96 + q0*4], pv[0]);
      ld4(&sPr[(r0+1)*96 + q1*4], pv[1]);
      ld4(&sPr[(r0+2)*96 + q2*4], pv[2]);
      ld4(&cur[(e0+0)*100 + kc*4], xv[0]);
      ld4(&cur[(e0+1)*100 + kc*4], xv[1]);
      #pragma unroll
      for (int rr = 0; rr < 3; ++rr)
        #pragma unroll
        for (int ee = 0; ee < 2; ++ee)
          #pragma unroll
          for (int s = 0; s < 4; ++s)
            acc[rr][ee] += pv[rr][s] * xv[ee][s];
    }

    if (it < 9) {
      // RMW: read old x from cur, write new x to nxt (no hazard: nobody
      // reads nxt this iteration) -> single barrier publishes it.
      #pragma unroll
      for (int rr = 0; rr < 3; ++rr) {
        int r = r0 + rr;
        float lo = (r < 64) ? -1000.0f : 0.0f;
        #pragma unroll
        for (int ee = 0; ee < 2; ++ee) {
          int e = e0 + ee;
          float y  = acc[rr][ee];
          float xo = cur[e*100 + r];
          float v  = 2.0f*y - xo;
          float zc = fminf(fmaxf(v, lo), 1000.0f);
          nxt[e*100 + r] = xo + zc - y;
        }
      }
      __syncthreads();
      float* tmp = cur; cur = nxt; nxt = tmp;
    } else {
      #pragma unroll
      for (int rr = 0; rr < 3; ++rr) {
        int r = r0 + rr;
        if (r < 64) {
          outg[(gbase + e0    )*64 + r] = acc[rr][0];
          outg[(gbase + e0 + 1)*64 + r] = acc[rr][1];
        }
      }
    }
  }
}

// ---------------------------------------------------------------- launch
extern "C" void kernel_launch(void* const* d_in, const int* in_sizes, int n_in,
                              void* d_out, int out_size, void* d_ws, size_t ws_size,
                              hipStream_t stream) {
  const float* x     = (const float*)d_in[0];   // (4096, 96)
  const float* parms = (const float*)d_in[1];   // (4096, 112)
  const float* Qg    = (const float*)d_in[2];   // (64, 64)
  const float* Ag    = (const float*)d_in[3];   // (16, 64)
  const float* Gg    = (const float*)d_in[4];   // (32, 64)
  float* out = (float*)d_out;                   // (4096, 64)

  float* ws  = (float*)d_ws;
  float* Pg  = ws;               // 96*96  = 9216
  float* Bg  = ws + 9216;        // 96*112 = 10752

  prep_kernel<<<1, 256, 0, stream>>>(Qg, Ag, Gg, Pg, Bg);
  iter_kernel<<<4096 / EB, 256, 0, stream>>>(x, parms, Pg, Bg, out);
}

// Round 5
// 90.849 us; speedup vs baseline: 2.2991x; 1.0550x over previous
//
#include <hip/hip_runtime.h>

// DR splitting solver. BATCH=4096, N=96 (64 x + 32 s), M=48 (16 eq + 32 ineq).
// JF and Hessian are batch-independent => prox_g1 is an affine map y = P x + Bmat p.
//   S=(I+Q)^{-1}; T=S Jx^T; K2=Jx T+diag(0,I32); R2=K2^{-1}[T^T|E];
//   P=diag(S,I)-[T;E^T]R2; Bmat=[-P[:,:64] | R2^T]
// Iterate 10x: y=Px+c; x += clamp(2y-x,l,u)-y; out=y[:64].
//
// Round-4 lesson: prep still latency/barrier-bound (~68 barriers x ~1kcy + div
// chains). Round-5: (a) double-buffered block-GJ -> 1 barrier/step; (b) rcp+NR
// divisions; (c) iter rewritten with P in REGISTERS (2 rows x 24 float4/thread,
// loaded once from L2) -- LDS only holds x (static dbuf) and parms.

__device__ __forceinline__ float dot4f(float4 a, float4 b) {
  return a.x*b.x + a.y*b.y + a.z*b.z + a.w*b.w;
}
__device__ __forceinline__ void ld4(const float* p, float* d) {
  float4 v = *(const float4*)p;
  d[0] = v.x; d[1] = v.y; d[2] = v.z; d[3] = v.w;
}
__device__ __forceinline__ void st4(float* p, const float* s) {
  *(float4*)p = make_float4(s[0], s[1], s[2], s[3]);
}
__device__ __forceinline__ float fastrcp(float x) {
  float r = __builtin_amdgcn_rcpf(x);
  return r * (2.0f - x * r);     // 1 Newton step: ~1e-7 rel
}
// W = A*B (4x4)
__device__ __forceinline__ void mm4(float W[4][4], const float A[4][4], const float B[4][4]) {
  #pragma unroll
  for (int r = 0; r < 4; ++r)
    #pragma unroll
    for (int q = 0; q < 4; ++q) {
      float s = A[r][0]*B[0][q];
      #pragma unroll
      for (int k = 1; k < 4; ++k) s += A[r][k]*B[k][q];
      W[r][q] = s;
    }
}
// in-place 4x4 inverse by GJ, no pivoting (SPD principal blocks)
__device__ __forceinline__ void inv4(float D[4][4]) {
  #pragma unroll
  for (int p = 0; p < 4; ++p) {
    float pi = fastrcp(D[p][p]);
    D[p][p] = pi;
    #pragma unroll
    for (int q = 0; q < 4; ++q) if (q != p) D[p][q] *= pi;
    #pragma unroll
    for (int i = 0; i < 4; ++i) if (i != p) {
      float f = D[i][p];
      #pragma unroll
      for (int q = 0; q < 4; ++q) if (q != p) D[i][q] -= f * D[p][q];
      D[i][p] = -f * pi;
    }
  }
}

// one double-buffered block-GJ step, stride 68 (64x64), all 256 threads
__device__ __forceinline__ void gj_step64(const float* __restrict__ src,
                                          float* __restrict__ dst,
                                          int b, int ig, int jg) {
  float D[4][4], C[4][4], R[4][4], T4[4][4], W[4][4];
  #pragma unroll
  for (int r = 0; r < 4; ++r) {
    ld4(&src[(4*b + r)*68 + 4*b],  D[r]);
    ld4(&src[(4*ig + r)*68 + 4*b], C[r]);
    ld4(&src[(4*b + r)*68 + 4*jg], R[r]);
    ld4(&src[(4*ig + r)*68 + 4*jg], T4[r]);
  }
  inv4(D);
  if (ig == b) {
    if (jg == b) {
      #pragma unroll
      for (int r = 0; r < 4; ++r)
        #pragma unroll
        for (int q = 0; q < 4; ++q) W[r][q] = D[r][q];
    } else {
      mm4(W, D, R);
    }
  } else {
    float E[4][4];
    mm4(E, C, D);
    if (jg == b) {
      #pragma unroll
      for (int r = 0; r < 4; ++r)
        #pragma unroll
        for (int q = 0; q < 4; ++q) W[r][q] = -E[r][q];
    } else {
      #pragma unroll
      for (int r = 0; r < 4; ++r)
        #pragma unroll
        for (int q = 0; q < 4; ++q) {
          float s = T4[r][q];
          #pragma unroll
          for (int k = 0; k < 4; ++k) s -= E[r][k] * R[k][q];
          W[r][q] = s;
        }
    }
  }
  #pragma unroll
  for (int r = 0; r < 4; ++r) st4(&dst[(4*ig + r)*68 + 4*jg], W[r]);
  __syncthreads();
}

// one double-buffered block-GJ step, stride 52 (48x48), threads 0..143 active
__device__ __forceinline__ void gj_step48(const float* __restrict__ src,
                                          float* __restrict__ dst,
                                          int b, int tid) {
  const bool act = tid < 144;
  const int ig = tid / 12, jg = tid - (tid / 12) * 12;
  float D[4][4], C[4][4], R[4][4], T4[4][4], W[4][4];
  if (act) {
    #pragma unroll
    for (int r = 0; r < 4; ++r) {
      ld4(&src[(4*b + r)*52 + 4*b],  D[r]);
      ld4(&src[(4*ig + r)*52 + 4*b], C[r]);
      ld4(&src[(4*b + r)*52 + 4*jg], R[r]);
      ld4(&src[(4*ig + r)*52 + 4*jg], T4[r]);
    }
    inv4(D);
    if (ig == b) {
      if (jg == b) {
        #pragma unroll
        for (int r = 0; r < 4; ++r)
          #pragma unroll
          for (int q = 0; q < 4; ++q) W[r][q] = D[r][q];
      } else {
        mm4(W, D, R);
      }
    } else {
      float E[4][4];
      mm4(E, C, D);
      if (jg == b) {
        #pragma unroll
        for (int r = 0; r < 4; ++r)
          #pragma unroll
          for (int q = 0; q < 4; ++q) W[r][q] = -E[r][q];
      } else {
        #pragma unroll
        for (int r = 0; r < 4; ++r)
          #pragma unroll
          for (int q = 0; q < 4; ++q) {
            float s = T4[r][q];
            #pragma unroll
            for (int k = 0; k < 4; ++k) s -= E[r][k] * R[k][q];
            W[r][q] = s;
          }
      }
    }
    #pragma unroll
    for (int r = 0; r < 4; ++r) st4(&dst[(4*ig + r)*52 + 4*jg], W[r]);
  }
  __syncthreads();
}

// ---------------------------------------------------------------- kernel A
__global__ __launch_bounds__(256, 1) void prep_kernel(
    const float* __restrict__ Qg, const float* __restrict__ Ag,
    const float* __restrict__ Gg,
    float* __restrict__ Pg, float* __restrict__ Bg)
{
  // floats: 4352 + 4352 + 2496 + 4608 = 15808 = 63232 B
  __shared__ float sMa[64*68];   // M1 ping  -> S (after 16 even steps)
  __shared__ float sMb[64*68];   // M1 pong  -> T (64x48, stride 48)
  __shared__ float sK [48*52];   // K2 ping  -> Ki
  __shared__ float sR2[48*96];   // Jx (stride 68) -> K2 pong (stride 52) -> R2 (stride 96)

#define SM_(i,j) sMa[(i)*68+(j)]
#define TT_(i,j) sMb[(i)*48+(j)]
#define SK_(i,j) sK[(i)*52+(j)]
#define JX_(a,k) sR2[(a)*68+(k)]

  const int tid = threadIdx.x;
  const int ig = tid >> 4, jg = tid & 15;

  // ---- stage Jx = [A;G] (48x64, stride 68) and M1 = Q + I
  {
    const float4* A4 = (const float4*)Ag;          // 256 quads
    const float4* G4 = (const float4*)Gg;          // 512 quads
    {
      int t = tid;
      int a = t >> 4, kc = t & 15;
      st4(&JX_(a, kc*4), (const float*)&A4[t]);
    }
    for (int t = tid; t < 512; t += 256) {
      int a = t >> 4, kc = t & 15;
      st4(&JX_(16 + a, kc*4), (const float*)&G4[t]);
    }
    const float4* Q4 = (const float4*)Qg;          // 1024 quads
    for (int t = tid; t < 1024; t += 256) {
      int i = t >> 4, kc = t & 15;
      st4(&SM_(i, kc*4), (const float*)&Q4[t]);
    }
  }
  __syncthreads();
  if (tid < 64) SM_(tid, tid) += 1.0f;
  __syncthreads();

  // ---- block-GJ 64 (double-buffered, 1 barrier/step, 16 steps) -> S in sMa
  #pragma unroll 1
  for (int p = 0; p < 8; ++p) {
    gj_step64(sMa, sMb, 2*p,     ig, jg);
    gj_step64(sMb, sMa, 2*p + 1, ig, jg);
  }

  // ---- T = S Jx^T : T[i][j] = sum_k S[i][k]*Jx[j][k]  (writes sMb, dead pong)
  #pragma unroll 1
  for (int t = tid; t < 64*48; t += 256) {
    int i = t / 48, j = t - i*48;
    float acc = 0.0f;
    #pragma unroll 1
    for (int k = 0; k < 64; k += 4)
      acc += dot4f(*(const float4*)&SM_(i,k), *(const float4*)&JX_(j,k));
    TT_(i,j) = acc;
  }
  __syncthreads();

  // ---- K2 = Jx T + diag(0,I32)  (192 threads, 3x4 tiles)
  if (tid < 192) {
    int ag = tid / 12, bg = tid - ag*12;
    int a0 = ag*3, b0 = bg*4;
    float acc[3][4] = {};
    #pragma unroll 1
    for (int k = 0; k < 64; ++k) {
      float4 tb = *(const float4*)&TT_(k,b0);
      #pragma unroll
      for (int r = 0; r < 3; ++r) {
        float jv = JX_(a0 + r, k);
        acc[r][0] += jv*tb.x; acc[r][1] += jv*tb.y;
        acc[r][2] += jv*tb.z; acc[r][3] += jv*tb.w;
      }
    }
    #pragma unroll
    for (int r = 0; r < 3; ++r)
      #pragma unroll
      for (int q = 0; q < 4; ++q) {
        int a = a0 + r, b = b0 + q;
        SK_(a,b) = acc[r][q] + ((a == b && a >= 16) ? 1.0f : 0.0f);
      }
  }
  __syncthreads();

  // ---- block-GJ 48 (double-buffered; pong overlays dead Jx region) -> Ki in sK
  {
    float* KP = sR2;   // 48*52 = 2496 <= 4608
    #pragma unroll 1
    for (int p = 0; p < 6; ++p) {
      gj_step48(sK, KP, 2*p,     tid);
      gj_step48(KP, sK, 2*p + 1, tid);
    }
  }
  // KP / JX dead; sR2 region becomes R2 (stride 96).

  // ---- R2 cols<64: R2[k][c] = sum_m Ki[k][m]*T[c][m]  (3k x 4c tiles)
  {
    int kg = tid >> 4, cg = tid & 15;
    int k0 = kg*3, c0 = cg*4;
    float acc[3][4] = {};
    #pragma unroll 1
    for (int m = 0; m < 48; m += 4) {
      float kv[3][4], tv[4][4];
      ld4(&SK_(k0+0,m), kv[0]); ld4(&SK_(k0+1,m), kv[1]); ld4(&SK_(k0+2,m), kv[2]);
      ld4(&TT_(c0+0,m), tv[0]); ld4(&TT_(c0+1,m), tv[1]);
      ld4(&TT_(c0+2,m), tv[2]); ld4(&TT_(c0+3,m), tv[3]);
      #pragma unroll
      for (int r = 0; r < 3; ++r)
        #pragma unroll
        for (int q = 0; q < 4; ++q)
          #pragma unroll
          for (int s = 0; s < 4; ++s)
            acc[r][q] += kv[r][s] * tv[q][s];
    }
    #pragma unroll
    for (int r = 0; r < 3; ++r)
      #pragma unroll
      for (int q = 0; q < 4; ++q) {
        int k = k0 + r, c = c0 + q;
        float v = acc[r][q];
        sR2[k*96 + c] = v;
        Bg[c*112 + 64 + k] = v;       // Bmat[:,64:] = R2^T
      }
  }
  // R2 cols>=64 (selection from Ki)
  for (int t = tid; t < 48*32; t += 256) {
    int k = t >> 5, j = t & 31;
    float v = SK_(k, 16 + j);
    sR2[k*96 + 64 + j] = v;
    Bg[(64 + j)*112 + 64 + k] = v;
  }
  __syncthreads();

  // ---- P heavy rows (i<64): P = S_diag - T*R2  (16 ig x 24 jc tasks)
  #pragma unroll 1
  for (int task = tid; task < 384; task += 256) {
    int tg = task / 24, jc = task - tg*24;
    int i0 = tg*4, j0 = jc*4;
    float acc[4][4];
    #pragma unroll
    for (int r = 0; r < 4; ++r)
      #pragma unroll
      for (int q = 0; q < 4; ++q)
        acc[r][q] = (j0 < 64) ? SM_(i0+r, j0+q) : 0.0f;
    #pragma unroll 1
    for (int m = 0; m < 48; m += 4) {
      float tv[4][4], rv[4][4];
      ld4(&TT_(i0+0,m), tv[0]); ld4(&TT_(i0+1,m), tv[1]);
      ld4(&TT_(i0+2,m), tv[2]); ld4(&TT_(i0+3,m), tv[3]);
      ld4(&sR2[(m+0)*96 + j0], rv[0]);
      ld4(&sR2[(m+1)*96 + j0], rv[1]);
      ld4(&sR2[(m+2)*96 + j0], rv[2]);
      ld4(&sR2[(m+3)*96 + j0], rv[3]);
      #pragma unroll
      for (int r = 0; r < 4; ++r)
        #pragma unroll
        for (int q = 0; q < 4; ++q)
          #pragma unroll
          for (int s = 0; s < 4; ++s)
            acc[r][q] -= tv[r][s] * rv[s][q];
    }
    #pragma unroll
    for (int r = 0; r < 4; ++r)
      #pragma unroll
      for (int q = 0; q < 4; ++q) {
        int i = i0 + r, j = j0 + q;
        float v = acc[r][q];
        Pg[i*96 + j] = v;
        if (j0 < 64) Bg[i*112 + j] = -v;   // Bmat[:,:64] = -P[:,:64]
      }
  }
  // ---- P rows >= 64: P[64+a][j] = (64+a==j) - R2[16+a][j]
  for (int t = tid; t < 32*96; t += 256) {
    int a = t / 96, j = t - a*96;
    float v = ((64 + a) == j ? 1.0f : 0.0f) - sR2[(16 + a)*96 + j];
    Pg[(64 + a)*96 + j] = v;
    if (j < 64) Bg[(64 + a)*112 + j] = -v;
  }
#undef SM_
#undef TT_
#undef SK_
#undef JX_
}

// ---------------------------------------------------------------- kernel B
#define EB 8   // elements per block; grid = 512 blocks x 192 threads

__global__ __launch_bounds__(192, 1) void iter_kernel(
    const float* __restrict__ xg, const float* __restrict__ pg,
    const float* __restrict__ Pg, const float* __restrict__ Bg,
    float* __restrict__ outg)
{
  // Each thread owns P rows {2tr, 2tr+1} IN REGISTERS (48 float4, from L2)
  // and elements {2te, 2te+1}. LDS holds only x (static dbuf) and parms.
  __shared__ float sX[2][EB][100];
  __shared__ float sPar[EB][112];

  const int tid = threadIdx.x;          // 0..191
  const int gbase = blockIdx.x * EB;
  const int tr = tid % 48;
  const int te = tid / 48;              // 0..3
  const int r0 = 2 * tr;                // rows r0, r0+1 (both <64 or both >=64)
  const int e0 = 2 * te;                // elems e0, e0+1

  // stage x (exactly 192 quads) and parms (224 quads)
  const float4* X4 = (const float4*)xg;
  {
    int e = tid / 24, kc = tid % 24;
    *(float4*)&sX[0][e][kc*4] = X4[gbase*24 + tid];
  }
  const float4* Par4 = (const float4*)pg;
  for (int t = tid; t < EB*28; t += 192) {
    int e = t / 28, jc = t - e*28;
    *(float4*)&sPar[e][jc*4] = Par4[gbase*28 + t];
  }

  // load my 2 P rows into registers (issued early; lands under c-phase)
  float4 pA[24], pB[24];
  const float4* P4 = (const float4*)Pg;
  #pragma unroll
  for (int kq = 0; kq < 24; ++kq) pA[kq] = P4[(r0    )*24 + kq];
  #pragma unroll
  for (int kq = 0; kq < 24; ++kq) pB[kq] = P4[(r0 + 1)*24 + kq];

  __syncthreads();

  // c = Bmat(rows r0,r0+1) @ parms(elems e0,e0+1), in registers
  float c00 = 0.f, c01 = 0.f, c10 = 0.f, c11 = 0.f;
  {
    const float4* B4 = (const float4*)Bg;
    #pragma unroll 1
    for (int jc = 0; jc < 28; ++jc) {
      float4 b0 = B4[(r0    )*28 + jc];
      float4 b1 = B4[(r0 + 1)*28 + jc];
      float4 q0 = *(const float4*)&sPar[e0    ][jc*4];
      float4 q1 = *(const float4*)&sPar[e0 + 1][jc*4];
      c00 += dot4f(b0, q0); c01 += dot4f(b0, q1);
      c10 += dot4f(b1, q0); c11 += dot4f(b1, q1);
    }
  }

  const float lo = (r0 < 64) ? -1000.0f : 0.0f;

  auto do_iter = [&](const float (*src)[100], float (*dst)[100], bool last) {
    float a00 = c00, a01 = c01, a10 = c10, a11 = c11;
    #pragma unroll
    for (int kq = 0; kq < 24; ++kq) {
      float4 x0 = *(const float4*)&src[e0    ][kq*4];
      float4 x1 = *(const float4*)&src[e0 + 1][kq*4];
      a00 += dot4f(pA[kq], x0); a01 += dot4f(pA[kq], x1);
      a10 += dot4f(pB[kq], x0); a11 += dot4f(pB[kq], x1);
    }
    if (!last) {
      float xo00 = src[e0    ][r0], xo10 = src[e0    ][r0 + 1];
      float xo01 = src[e0 + 1][r0], xo11 = src[e0 + 1][r0 + 1];
      float z00 = fminf(fmaxf(2.f*a00 - xo00, lo), 1000.f);
      float z10 = fminf(fmaxf(2.f*a10 - xo10, lo), 1000.f);
      float z01 = fminf(fmaxf(2.f*a01 - xo01, lo), 1000.f);
      float z11 = fminf(fmaxf(2.f*a11 - xo11, lo), 1000.f);
      dst[e0    ][r0    ] = xo00 + z00 - a00;
      dst[e0    ][r0 + 1] = xo10 + z10 - a10;
      dst[e0 + 1][r0    ] = xo01 + z01 - a01;
      dst[e0 + 1][r0 + 1] = xo11 + z11 - a11;
      __syncthreads();
    } else {
      if (r0 < 64) {
        *(float2*)&outg[(gbase + e0    )*64 + r0] = make_float2(a00, a10);
        *(float2*)&outg[(gbase + e0 + 1)*64 + r0] = make_float2(a01, a11);
      }
    }
  };

  do_iter(sX[0], sX[1], false);   // it 0
  do_iter(sX[1], sX[0], false);   // it 1
  do_iter(sX[0], sX[1], false);   // it 2
  do_iter(sX[1], sX[0], false);   // it 3
  do_iter(sX[0], sX[1], false);   // it 4
  do_iter(sX[1], sX[0], false);   // it 5
  do_iter(sX[0], sX[1], false);   // it 6
  do_iter(sX[1], sX[0], false);   // it 7
  do_iter(sX[0], sX[1], false);   // it 8
  do_iter(sX[1], sX[0], true);    // it 9 -> output
}

// ---------------------------------------------------------------- launch
extern "C" void kernel_launch(void* const* d_in, const int* in_sizes, int n_in,
                              void* d_out, int out_size, void* d_ws, size_t ws_size,
                              hipStream_t stream) {
  const float* x     = (const float*)d_in[0];   // (4096, 96)
  const float* parms = (const float*)d_in[1];   // (4096, 112)
  const float* Qg    = (const float*)d_in[2];   // (64, 64)
  const float* Ag    = (const float*)d_in[3];   // (16, 64)
  const float* Gg    = (const float*)d_in[4];   // (32, 64)
  float* out = (float*)d_out;                   // (4096, 64)

  float* ws  = (float*)d_ws;
  float* Pg  = ws;               // 96*96  = 9216
  float* Bg  = ws + 9216;        // 96*112 = 10752

  prep_kernel<<<1, 256, 0, stream>>>(Qg, Ag, Gg, Pg, Bg);
  iter_kernel<<<4096 / EB, 192, 0, stream>>>(x, parms, Pg, Bg, out);
}